// Round 15
// baseline (68.060 us; speedup 1.0000x reference)
//
#include <hip/hip_runtime.h>

// PSRoIPool — raw f32 inputs, f32 compute, bin size via RECIPROCAL-MULTIPLY.
// R13 PASSED: the golden lowers /7 to * fl(1/7). The geometry chain —
// especially `* rcp7` — is semantics-bearing. DO NOT CHANGE IT.
//
// R15 perf change: 16 lanes per bin (4 rows x 4 cols) instead of 8.
// Halves the worst-case per-lane gather count (tail latency) and doubles
// the grid to 3136 blocks (~12/CU) for latency hiding. 4-step shfl_xor
// reduce. dur_us is near the harness floor (268 MB ws-poison fill = 42 µs
// dominates the profile); this is the last kernel-side lever.

#define GS 7   // group size G
#define DD 8   // D = C / (G*G)
#define BB 2   // batch
#define HH 50
#define WW 84

__global__ void psroi_kernel(const float* __restrict__ rois,
                             const float* __restrict__ feat,
                             const int*   __restrict__ stride_ptr,
                             float*       __restrict__ out,
                             int nbins) {
    // Single-rounded ops only — no implicit FMA contraction (semantics).
    #pragma clang fp contract(off)

    int t = blockIdx.x * blockDim.x + threadIdx.x;
    int bin  = t >> 4;        // 16 lanes per bin
    int lane = t & 15;
    if (bin >= nbins) return;

    int j = bin % GS;
    int i = (bin / GS) % GS;
    int d = (bin / (GS * GS)) % DD;
    int n = bin / (GS * GS * DD);

    float scale = 1.0f / (float)(*stride_ptr);   // 1/16 exact

    const float* r = rois + (size_t)n * 5;

    // batch index (0/1); clamp defensively against OOB.
    int b = (int)r[0];
    b = b < 0 ? 0 : (b > (BB - 1) ? (BB - 1) : b);

    // Geometry in f32 on raw inputs (np.round = half-even = rintf).
    float xs = rintf(r[1]) * scale;
    float ys = rintf(r[2]) * scale;
    float xe = (rintf(r[3]) + 1.0f) * scale;
    float ye = (rintf(r[4]) + 1.0f) * scale;

    // Semantics-critical: golden computes /7 as multiply by fl(1/7).
    const float rcp7 = 1.0f / 7.0f;
    float bin_w = fmaxf(xe - xs, 0.1f) * rcp7;
    float bin_h = fmaxf(ye - ys, 0.1f) * rcp7;

    float jf = (float)j;
    float fi = (float)i;

    float wstart = fminf(fmaxf(floorf(jf * bin_w + xs), 0.0f), (float)WW);
    float wend   = fminf(fmaxf(ceilf((jf + 1.0f) * bin_w + xs), 0.0f), (float)WW);
    float hstart = fminf(fmaxf(floorf(fi * bin_h + ys), 0.0f), (float)HH);
    float hend   = fminf(fmaxf(ceilf((fi + 1.0f) * bin_h + ys), 0.0f), (float)HH);

    float area = fmaxf((hend - hstart) * (wend - wstart), 1.0f);

    int hs = (int)hstart, he = (int)hend;
    int ws = (int)wstart, we = (int)wend;

    int c = (d * GS + i) * GS + j;   // position-sensitive channel
    const float* fbase = feat + ((size_t)b * (DD * GS * GS) + c) * (HH * WW);

    // 4x4 lane tile over the bin: lh in {0..3}, lw in {0..3}.
    int lh = lane >> 2;
    int lw = lane & 3;

    float sum = 0.0f;
    for (int h = hs + lh; h < he; h += 4) {
        const float* row = fbase + (size_t)h * WW;
        for (int w = ws + lw; w < we; w += 4) {
            sum += row[w];
        }
    }

    // Reduce across the 16-lane group (xor masks stay within the group).
    sum += __shfl_xor(sum, 1, 64);
    sum += __shfl_xor(sum, 2, 64);
    sum += __shfl_xor(sum, 4, 64);
    sum += __shfl_xor(sum, 8, 64);

    if (lane == 0) out[bin] = sum / area;
}

extern "C" void kernel_launch(void* const* d_in, const int* in_sizes, int n_in,
                              void* d_out, int out_size, void* d_ws, size_t ws_size,
                              hipStream_t stream) {
    const float* rois   = (const float*)d_in[0];
    const float* feat   = (const float*)d_in[1];
    const int*   stride = (const int*)d_in[2];
    float*       out    = (float*)d_out;

    int nbins = out_size;               // N * D * G * G = 50176
    long long threads = (long long)nbins * 16;
    int block = 256;
    int grid  = (int)((threads + block - 1) / block);   // 3136 blocks
    psroi_kernel<<<grid, block, 0, stream>>>(rois, feat, stride, out, nbins);
}